// Round 4
// baseline (414.319 us; speedup 1.0000x reference)
//
#include <hip/hip_runtime.h>
#include <hip/hip_bf16.h>

#define TT 36
#define KK 160
#define NPOLE 40
#define PP 4096
#define MAXIT 100
#define COLS 16
#define NW 5
#define NTHR 320
#define YS 168   // bf16 stride per column (padded from 160)
#define GRID 512

// ws float offsets
#define WS_LINV  0
#define WS_LAMBD 1
#define WS_TTS   2      // 100 floats
#define WS_KSTAR 128    // int
#define WS_FROB  132    // float, atomicAdd accumulator
#define WS_PART  160    // 100 floats, atomicAdd-accumulated per-iter norm^2
#define WS_D     512    // 36*160 fp32
#define WS_A     6400   // 160*160 fp32 (DtD scratch)
#define WS_AH    32000  // 160*160 bf16 hi (as shorts)
#define WS_AL    44800  // 160*160 bf16 lo

typedef float  floatx4 __attribute__((ext_vector_type(4)));
typedef short  shortx8 __attribute__((ext_vector_type(8)));

__device__ __forceinline__ short f2bf(float v) {
  unsigned u = __float_as_uint(v);
  unsigned r = (u + 0x7FFFu + ((u >> 16) & 1u)) >> 16;  // RNE
  return (short)r;
}
__device__ __forceinline__ float bf2f(short s) {
  return __uint_as_float(((unsigned)(unsigned short)s) << 16);
}

// ---- setup 1: build normalized D, tts, zero accumulators (1 block) ----
__global__ void setup1(const float* __restrict__ Drr,
                       const float* __restrict__ Dth,
                       float* __restrict__ ws) {
  __shared__ float Dl[TT * KK];
  __shared__ float Gl[KK];
  const int tid = threadIdx.x;
  for (int i = tid; i < MAXIT; i += 256) ws[WS_PART + i] = 0.f;
  if (tid == 0) ws[WS_FROB] = 0.f;

  for (int idx = tid; idx < TT * KK; idx += 256) {
    int i = idx / KK, k = idx % KK;
    int g = k / NPOLE, n = k % NPOLE;
    float rr = Drr[n], th = Dth[n];
    float pr = powf(rr, (float)i);
    float ang = (float)i * th;
    float tri = (g < 2) ? cosf(ang) : sinf(ang);
    float sgn = ((g & 1) && (i & 1)) ? -1.0f : 1.0f;
    Dl[idx] = pr * tri * sgn;
  }
  __syncthreads();
  if (tid < KK) {
    float s = 0.f;
    for (int i = 0; i < TT; i++) { float v = Dl[i * KK + tid]; s += v * v; }
    float gn = sqrtf(s);
    Gl[tid] = (gn == 0.f) ? sqrtf((float)TT) : gn;
  }
  __syncthreads();
  for (int idx = tid; idx < TT * KK; idx += 256)
    ws[WS_D + idx] = Dl[idx] / Gl[idx % KK];

  if (tid == 0) {
    double ts = 1.0;
    for (int k = 0; k < MAXIT; k++) {
      double tn = (1.0 + sqrt(1.0 + 4.0 * ts * ts)) * 0.5;
      ws[WS_TTS + k] = (float)((ts - 1.0) / tn);
      ts = tn;
    }
  }
}

// ---- setup 2: DtD row per block + Frobenius^2 accumulation (160 blocks) ----
__global__ void setup2(float* __restrict__ ws) {
  __shared__ float red[256];
  const int a = blockIdx.x, b = threadIdx.x;
  const float* D = &ws[WS_D];
  float ss = 0.f;
  if (b < KK) {
    float s = 0.f;
    for (int t = 0; t < TT; t++) s += D[t * KK + a] * D[t * KK + b];
    ws[WS_A + a * KK + b] = s;
    ss = s * s;
  }
  red[b] = ss;
  __syncthreads();
  for (int off = 128; off > 0; off >>= 1) {
    if (b < off) red[b] += red[b + off];
    __syncthreads();
  }
  if (b == 0) atomicAdd(&ws[WS_FROB], red[0]);
}

// ---- setup 3: A = I - DtD/L split to bf16 hi/lo (100 blocks) ----
__global__ void setup3(float* __restrict__ ws) {
  const int idx = blockIdx.x * 256 + threadIdx.x;
  const float linv = 1.0f / sqrtf(ws[WS_FROB]);
  short* AHs = (short*)&ws[WS_AH];
  short* ALs = (short*)&ws[WS_AL];
  if (idx < KK * KK) {
    int a = idx / KK, b = idx % KK;
    float av = ((a == b) ? 1.0f : 0.0f) - ws[WS_A + idx] * linv;
    short h = f2bf(av);
    AHs[idx] = h;
    ALs[idx] = f2bf(av - bf2f(h));
  }
  if (idx == 0) { ws[WS_LINV] = linv; ws[WS_LAMBD] = 0.1f * linv; }
}

// Block: 16 columns, 5 waves; wave w owns rows 32w..32w+31 (2 fragments).
// A in registers (bf16 hi/lo); y double-buffered in LDS bf16 hi/lo.
// One barrier per iteration; 512 blocks -> 2 blocks/CU for overlap.
__global__ __launch_bounds__(NTHR, 3)
void fista_kernel(const float* __restrict__ x, float* __restrict__ out,
                  float* __restrict__ ws, int mode) {
  __shared__ __align__(16) short ys[2][2][COLS * YS];  // 21,504 B
  __shared__ float red[2][NW];
  __shared__ float ttsl[MAXIT];

  int niter = MAXIT;
  if (mode == 1) {
    int kstar = *(const int*)&ws[WS_KSTAR];
    if (kstar >= MAXIT - 1) return;
    niter = kstar + 1;
  }

  const int tid  = threadIdx.x;
  const int w    = tid >> 6;
  const int lane = tid & 63;
  const int quad = lane >> 4;
  const int l16  = lane & 15;
  const int bid  = blockIdx.x;
  const int c0   = bid * COLS;
  const int bb   = c0 / PP;
  const int p0   = c0 % PP;
  const float linv  = ws[WS_LINV];
  const float lambd = ws[WS_LAMBD];

  for (int i = tid; i < MAXIT; i += NTHR) ttsl[i] = ws[WS_TTS + i];

  // A fragments in registers: rowset rs covers rows 32w+16rs .. +15
  const short* AH = (const short*)&ws[WS_AH];
  const short* AL = (const short*)&ws[WS_AL];
  shortx8 ah[2][5], al[2][5];
#pragma unroll
  for (int rs = 0; rs < 2; rs++)
#pragma unroll
    for (int kc = 0; kc < 5; kc++) {
      int off = (32 * w + 16 * rs + l16) * KK + 32 * kc + 8 * quad;
      ah[rs][kc] = *(const shortx8*)&AH[off];
      al[rs][kc] = *(const shortx8*)&AL[off];
    }

  // dty (scaled by linv) in C layout: rows 32w+16rs+4quad+r, col l16
  const float* Dg = &ws[WS_D];
  float dty[2][4] = {{0.f,0.f,0.f,0.f},{0.f,0.f,0.f,0.f}};
  {
    const float* xcol = &x[(size_t)bb * TT * PP + p0 + l16];
    for (int t = 0; t < TT; t++) {
      float xv = xcol[(size_t)t * PP];
      float4 d0 = *(const float4*)&Dg[t * KK + 32 * w + 4 * quad];
      float4 d1 = *(const float4*)&Dg[t * KK + 32 * w + 16 + 4 * quad];
      dty[0][0] = fmaf(d0.x, xv, dty[0][0]);
      dty[0][1] = fmaf(d0.y, xv, dty[0][1]);
      dty[0][2] = fmaf(d0.z, xv, dty[0][2]);
      dty[0][3] = fmaf(d0.w, xv, dty[0][3]);
      dty[1][0] = fmaf(d1.x, xv, dty[1][0]);
      dty[1][1] = fmaf(d1.y, xv, dty[1][1]);
      dty[1][2] = fmaf(d1.z, xv, dty[1][2]);
      dty[1][3] = fmaf(d1.w, xv, dty[1][3]);
    }
#pragma unroll
    for (int rs = 0; rs < 2; rs++)
#pragma unroll
      for (int r = 0; r < 4; r++) dty[rs][r] *= linv;
  }

  // zero buffer 0 (y=0); buffer 1 fully overwritten before first read
  {
    int* z = (int*)&ys[0][0][0];
    for (int i = tid; i < COLS * YS; i += NTHR) z[i] = 0;
  }
  float xo[2][4] = {{0.f,0.f,0.f,0.f},{0.f,0.f,0.f,0.f}};
  __syncthreads();

  int buf = 0;
  for (int it = 0; it < niter; it++) {
    const short* yh = &ys[buf][0][0];
    const short* ylp = &ys[buf][1][0];
    const int cb = l16 * YS + 8 * quad;
    floatx4 accA[2] = {{0.f,0.f,0.f,0.f},{0.f,0.f,0.f,0.f}};
    floatx4 accB[2] = {{0.f,0.f,0.f,0.f},{0.f,0.f,0.f,0.f}};
#pragma unroll
    for (int kc = 0; kc < 5; kc++) {
      shortx8 bh = *(const shortx8*)&yh[cb + 32 * kc];
      shortx8 bl = *(const shortx8*)&ylp[cb + 32 * kc];
#pragma unroll
      for (int rs = 0; rs < 2; rs++) {
        accA[rs] = __builtin_amdgcn_mfma_f32_16x16x32_bf16(ah[rs][kc], bh, accA[rs], 0, 0, 0);
        accB[rs] = __builtin_amdgcn_mfma_f32_16x16x32_bf16(ah[rs][kc], bl, accB[rs], 0, 0, 0);
        accB[rs] = __builtin_amdgcn_mfma_f32_16x16x32_bf16(al[rs][kc], bh, accB[rs], 0, 0, 0);
      }
    }

    const float tt = ttsl[it];
    const int nb = buf ^ 1;
    float lsum = 0.f;
#pragma unroll
    for (int rs = 0; rs < 2; rs++) {
      float yn[4];
#pragma unroll
      for (int r = 0; r < 4; r++) {
        float v  = accA[rs][r] + accB[rs][r] + dty[rs][r];
        float aa = fabsf(v) - lambd;
        float xv = (aa > 0.f) ? ((v < 0.f) ? -aa : aa) : 0.f;
        float dd = xv - xo[rs][r];
        lsum = fmaf(dd, dd, lsum);
        yn[r] = fmaf(tt, dd, xv);
        xo[rs][r] = xv;
      }
      __hip_bfloat162 h01 = __float22bfloat162_rn(make_float2(yn[0], yn[1]));
      __hip_bfloat162 h23 = __float22bfloat162_rn(make_float2(yn[2], yn[3]));
      unsigned u01 = *(unsigned*)&h01;
      unsigned u23 = *(unsigned*)&h23;
      float r0f = yn[0] - __uint_as_float(u01 << 16);
      float r1f = yn[1] - __uint_as_float(u01 & 0xffff0000u);
      float r2f = yn[2] - __uint_as_float(u23 << 16);
      float r3f = yn[3] - __uint_as_float(u23 & 0xffff0000u);
      __hip_bfloat162 l01 = __float22bfloat162_rn(make_float2(r0f, r1f));
      __hip_bfloat162 l23 = __float22bfloat162_rn(make_float2(r2f, r3f));
      const int ko = l16 * YS + 32 * w + 16 * rs + 4 * quad;
      *(uint2*)&ys[nb][0][ko] = make_uint2(*(unsigned*)&l01 * 0u + u01, u23);
      *(uint2*)&ys[nb][1][ko] = make_uint2(*(unsigned*)&l01, *(unsigned*)&l23);
    }

    if (mode == 0) {
#pragma unroll
      for (int off = 32; off > 0; off >>= 1) lsum += __shfl_down(lsum, off, 64);
      if (lane == 0) red[it & 1][w] = lsum;
    }
    __syncthreads();   // writes to buf^1 (+red) visible; reads of buf done
    if (mode == 0 && tid == 0) {
      float s = 0.f;
#pragma unroll
      for (int i = 0; i < NW; i++) s += red[it & 1][i];
      atomicAdd(&ws[WS_PART + it], s);
    }
    buf = nb;
  }

#pragma unroll
  for (int rs = 0; rs < 2; rs++)
#pragma unroll
    for (int r = 0; r < 4; r++)
      out[((size_t)bb * KK + 32 * w + 16 * rs + 4 * quad + r) * PP + p0 + l16] = xo[rs][r];
}

__global__ void conv_scan(float* __restrict__ ws) {
  __shared__ unsigned char conv[MAXIT];
  const int tid = threadIdx.x;
  if (tid < MAXIT) {
    float s = ws[WS_PART + tid];
    float denom = (tid == 0) ? 4096.0f : 160.0f;
    conv[tid] = (sqrtf(s) / denom < 1e-4f) ? 1 : 0;
  }
  __syncthreads();
  if (tid == 0) {
    int kstar = MAXIT;
    for (int it = 0; it < MAXIT; it++)
      if (conv[it]) { kstar = it; break; }
    *reinterpret_cast<int*>(&ws[WS_KSTAR]) = kstar;
  }
}

extern "C" void kernel_launch(void* const* d_in, const int* in_sizes, int n_in,
                              void* d_out, int out_size, void* d_ws, size_t ws_size,
                              hipStream_t stream) {
  const float* Drr = (const float*)d_in[0];
  const float* Dth = (const float*)d_in[1];
  const float* x   = (const float*)d_in[2];
  float* out = (float*)d_out;
  float* ws  = (float*)d_ws;

  setup1<<<1, 256, 0, stream>>>(Drr, Dth, ws);
  setup2<<<160, 256, 0, stream>>>(ws);
  setup3<<<100, 256, 0, stream>>>(ws);
  fista_kernel<<<GRID, NTHR, 0, stream>>>(x, out, ws, 0);
  conv_scan<<<1, 128, 0, stream>>>(ws);
  fista_kernel<<<GRID, NTHR, 0, stream>>>(x, out, ws, 1);
}

// Round 5
// 378.261 us; speedup vs baseline: 1.0953x; 1.0953x over previous
//
#include <hip/hip_runtime.h>
#include <hip/hip_bf16.h>

#define TT 36
#define KK 160
#define NPOLE 40
#define PP 4096
#define MAXIT 100
#define COLS 16
#define NW 5
#define NTHR 320
#define YS 168   // bf16 stride per column (padded from 160)
#define GRID 512

// ws float offsets
#define WS_LINV  0
#define WS_LAMBD 1
#define WS_TTS   2      // 100 floats
#define WS_KSTAR 128    // int
#define WS_FROB  132    // float, atomicAdd accumulator (setup only)
#define WS_CONVF 256    // 100 floats: convergence flags
#define WS_D     512    // 36*160 fp32
#define WS_A     6400   // 160*160 fp32 (DtD scratch)
#define WS_AH    32000  // 160*160 bf16 hi (as shorts)
#define WS_AL    44800  // 160*160 bf16 lo
#define WS_PART2 57600  // [it][bid] 100*512 floats
// end: 108800 floats = 435,200 B

typedef float  floatx4 __attribute__((ext_vector_type(4)));
typedef short  shortx8 __attribute__((ext_vector_type(8)));

__device__ __forceinline__ short f2bf(float v) {
  unsigned u = __float_as_uint(v);
  unsigned r = (u + 0x7FFFu + ((u >> 16) & 1u)) >> 16;  // RNE
  return (short)r;
}
__device__ __forceinline__ float bf2f(short s) {
  return __uint_as_float(((unsigned)(unsigned short)s) << 16);
}

// ---- setup 1: build normalized D, tts (1 block) ----
__global__ void setup1(const float* __restrict__ Drr,
                       const float* __restrict__ Dth,
                       float* __restrict__ ws) {
  __shared__ float Dl[TT * KK];
  __shared__ float Gl[KK];
  const int tid = threadIdx.x;
  if (tid == 0) ws[WS_FROB] = 0.f;

  for (int idx = tid; idx < TT * KK; idx += 256) {
    int i = idx / KK, k = idx % KK;
    int g = k / NPOLE, n = k % NPOLE;
    float rr = Drr[n], th = Dth[n];
    float pr = powf(rr, (float)i);
    float ang = (float)i * th;
    float tri = (g < 2) ? cosf(ang) : sinf(ang);
    float sgn = ((g & 1) && (i & 1)) ? -1.0f : 1.0f;
    Dl[idx] = pr * tri * sgn;
  }
  __syncthreads();
  if (tid < KK) {
    float s = 0.f;
    for (int i = 0; i < TT; i++) { float v = Dl[i * KK + tid]; s += v * v; }
    float gn = sqrtf(s);
    Gl[tid] = (gn == 0.f) ? sqrtf((float)TT) : gn;
  }
  __syncthreads();
  for (int idx = tid; idx < TT * KK; idx += 256)
    ws[WS_D + idx] = Dl[idx] / Gl[idx % KK];

  if (tid == 0) {
    double ts = 1.0;
    for (int k = 0; k < MAXIT; k++) {
      double tn = (1.0 + sqrt(1.0 + 4.0 * ts * ts)) * 0.5;
      ws[WS_TTS + k] = (float)((ts - 1.0) / tn);
      ts = tn;
    }
  }
}

// ---- setup 2: DtD row per block + Frobenius^2 accumulation (160 blocks) ----
__global__ void setup2(float* __restrict__ ws) {
  __shared__ float red[256];
  const int a = blockIdx.x, b = threadIdx.x;
  const float* D = &ws[WS_D];
  float ss = 0.f;
  if (b < KK) {
    float s = 0.f;
    for (int t = 0; t < TT; t++) s += D[t * KK + a] * D[t * KK + b];
    ws[WS_A + a * KK + b] = s;
    ss = s * s;
  }
  red[b] = ss;
  __syncthreads();
  for (int off = 128; off > 0; off >>= 1) {
    if (b < off) red[b] += red[b + off];
    __syncthreads();
  }
  if (b == 0) atomicAdd(&ws[WS_FROB], red[0]);
}

// ---- setup 3: A = I - DtD/L split to bf16 hi/lo (100 blocks) ----
__global__ void setup3(float* __restrict__ ws) {
  const int idx = blockIdx.x * 256 + threadIdx.x;
  const float linv = 1.0f / sqrtf(ws[WS_FROB]);
  short* AHs = (short*)&ws[WS_AH];
  short* ALs = (short*)&ws[WS_AL];
  if (idx < KK * KK) {
    int a = idx / KK, b = idx % KK;
    float av = ((a == b) ? 1.0f : 0.0f) - ws[WS_A + idx] * linv;
    short h = f2bf(av);
    AHs[idx] = h;
    ALs[idx] = f2bf(av - bf2f(h));
  }
  if (idx == 0) { ws[WS_LINV] = linv; ws[WS_LAMBD] = 0.1f * linv; }
}

// Block: 16 columns, 5 waves; wave w owns rows 32w..32w+31 (2 fragments).
// A in registers (bf16 hi/lo); y double-buffered in LDS bf16 hi/lo.
// NO global memory ops inside the iteration loop: per-iter norms go to an
// LDS array, burst-written at the end (mode 0).
__global__ __launch_bounds__(NTHR, 3)
void fista_kernel(const float* __restrict__ x, float* __restrict__ out,
                  float* __restrict__ ws, int mode) {
  __shared__ __align__(16) short ys[2][2][COLS * YS];  // 21,504 B
  __shared__ float red[2][NW];
  __shared__ float ttsl[MAXIT];
  __shared__ float parts[MAXIT];

  int niter = MAXIT;
  if (mode == 1) {
    int kstar = *(const int*)&ws[WS_KSTAR];
    if (kstar >= MAXIT - 1) return;
    niter = kstar + 1;
  }

  const int tid  = threadIdx.x;
  const int w    = tid >> 6;
  const int lane = tid & 63;
  const int quad = lane >> 4;
  const int l16  = lane & 15;
  const int bid  = blockIdx.x;
  const int c0   = bid * COLS;
  const int bb   = c0 / PP;
  const int p0   = c0 % PP;
  const float linv  = ws[WS_LINV];
  const float lambd = ws[WS_LAMBD];

  for (int i = tid; i < MAXIT; i += NTHR) ttsl[i] = ws[WS_TTS + i];

  // A fragments in registers: rowset rs covers rows 32w+16rs .. +15
  const short* AH = (const short*)&ws[WS_AH];
  const short* AL = (const short*)&ws[WS_AL];
  shortx8 ah[2][5], al[2][5];
#pragma unroll
  for (int rs = 0; rs < 2; rs++)
#pragma unroll
    for (int kc = 0; kc < 5; kc++) {
      int off = (32 * w + 16 * rs + l16) * KK + 32 * kc + 8 * quad;
      ah[rs][kc] = *(const shortx8*)&AH[off];
      al[rs][kc] = *(const shortx8*)&AL[off];
    }

  // dty (scaled by linv) in C layout: rows 32w+16rs+4quad+r, col l16
  const float* Dg = &ws[WS_D];
  float dty[2][4] = {{0.f,0.f,0.f,0.f},{0.f,0.f,0.f,0.f}};
  {
    const float* xcol = &x[(size_t)bb * TT * PP + p0 + l16];
    for (int t = 0; t < TT; t++) {
      float xv = xcol[(size_t)t * PP];
      float4 d0 = *(const float4*)&Dg[t * KK + 32 * w + 4 * quad];
      float4 d1 = *(const float4*)&Dg[t * KK + 32 * w + 16 + 4 * quad];
      dty[0][0] = fmaf(d0.x, xv, dty[0][0]);
      dty[0][1] = fmaf(d0.y, xv, dty[0][1]);
      dty[0][2] = fmaf(d0.z, xv, dty[0][2]);
      dty[0][3] = fmaf(d0.w, xv, dty[0][3]);
      dty[1][0] = fmaf(d1.x, xv, dty[1][0]);
      dty[1][1] = fmaf(d1.y, xv, dty[1][1]);
      dty[1][2] = fmaf(d1.z, xv, dty[1][2]);
      dty[1][3] = fmaf(d1.w, xv, dty[1][3]);
    }
#pragma unroll
    for (int rs = 0; rs < 2; rs++)
#pragma unroll
      for (int r = 0; r < 4; r++) dty[rs][r] *= linv;
  }

  // zero buffer 0 (y=0); buffer 1 fully overwritten before first read
  {
    int* z = (int*)&ys[0][0][0];
    for (int i = tid; i < COLS * YS; i += NTHR) z[i] = 0;
  }
  float xo[2][4] = {{0.f,0.f,0.f,0.f},{0.f,0.f,0.f,0.f}};
  __syncthreads();

  int buf = 0;
  for (int it = 0; it < niter; it++) {
    const short* yh = &ys[buf][0][0];
    const short* ylp = &ys[buf][1][0];
    const int cb = l16 * YS + 8 * quad;
    floatx4 accA[2] = {{0.f,0.f,0.f,0.f},{0.f,0.f,0.f,0.f}};
    floatx4 accB[2] = {{0.f,0.f,0.f,0.f},{0.f,0.f,0.f,0.f}};
#pragma unroll
    for (int kc = 0; kc < 5; kc++) {
      shortx8 bh = *(const shortx8*)&yh[cb + 32 * kc];
      shortx8 bl = *(const shortx8*)&ylp[cb + 32 * kc];
#pragma unroll
      for (int rs = 0; rs < 2; rs++) {
        accA[rs] = __builtin_amdgcn_mfma_f32_16x16x32_bf16(ah[rs][kc], bh, accA[rs], 0, 0, 0);
        accB[rs] = __builtin_amdgcn_mfma_f32_16x16x32_bf16(ah[rs][kc], bl, accB[rs], 0, 0, 0);
        accB[rs] = __builtin_amdgcn_mfma_f32_16x16x32_bf16(al[rs][kc], bh, accB[rs], 0, 0, 0);
      }
    }

    const float tt = ttsl[it];
    const int nb = buf ^ 1;
    float lsum = 0.f;
#pragma unroll
    for (int rs = 0; rs < 2; rs++) {
      float yn[4];
#pragma unroll
      for (int r = 0; r < 4; r++) {
        float v  = accA[rs][r] + accB[rs][r] + dty[rs][r];
        float aa = fabsf(v) - lambd;
        float xv = (aa > 0.f) ? ((v < 0.f) ? -aa : aa) : 0.f;
        float dd = xv - xo[rs][r];
        lsum = fmaf(dd, dd, lsum);
        yn[r] = fmaf(tt, dd, xv);
        xo[rs][r] = xv;
      }
      __hip_bfloat162 h01 = __float22bfloat162_rn(make_float2(yn[0], yn[1]));
      __hip_bfloat162 h23 = __float22bfloat162_rn(make_float2(yn[2], yn[3]));
      unsigned u01 = *(unsigned*)&h01;
      unsigned u23 = *(unsigned*)&h23;
      float r0f = yn[0] - __uint_as_float(u01 << 16);
      float r1f = yn[1] - __uint_as_float(u01 & 0xffff0000u);
      float r2f = yn[2] - __uint_as_float(u23 << 16);
      float r3f = yn[3] - __uint_as_float(u23 & 0xffff0000u);
      __hip_bfloat162 l01 = __float22bfloat162_rn(make_float2(r0f, r1f));
      __hip_bfloat162 l23 = __float22bfloat162_rn(make_float2(r2f, r3f));
      const int ko = l16 * YS + 32 * w + 16 * rs + 4 * quad;
      *(uint2*)&ys[nb][0][ko] = make_uint2(u01, u23);
      *(uint2*)&ys[nb][1][ko] = make_uint2(*(unsigned*)&l01, *(unsigned*)&l23);
    }

    if (mode == 0) {
#pragma unroll
      for (int off = 32; off > 0; off >>= 1) lsum += __shfl_down(lsum, off, 64);
      if (lane == 0) red[it & 1][w] = lsum;
    }
    __syncthreads();   // writes to buf^1 (+red) visible; reads of buf done
    if (mode == 0 && tid == 0) {
      float s = 0.f;
#pragma unroll
      for (int i = 0; i < NW; i++) s += red[it & 1][i];
      parts[it] = s;   // LDS only — no global traffic in the loop
    }
    buf = nb;
  }

#pragma unroll
  for (int rs = 0; rs < 2; rs++)
#pragma unroll
    for (int r = 0; r < 4; r++)
      out[((size_t)bb * KK + 32 * w + 16 * rs + 4 * quad + r) * PP + p0 + l16] = xo[rs][r];

  if (mode == 0) {
    __syncthreads();   // parts[] complete
    if (tid < MAXIT) ws[WS_PART2 + tid * GRID + bid] = parts[tid];
  }
}

// ---- reduce per-iter norms across 512 blocks (100 blocks x 512 thr) ----
__global__ void conv_reduce(float* __restrict__ ws) {
  __shared__ float red[512];
  const int it = blockIdx.x, tid = threadIdx.x;
  red[tid] = ws[WS_PART2 + it * GRID + tid];
  __syncthreads();
  for (int off = 256; off > 0; off >>= 1) {
    if (tid < off) red[tid] += red[tid + off];
    __syncthreads();
  }
  if (tid == 0) {
    float denom = (it == 0) ? 4096.0f : 160.0f;
    ws[WS_CONVF + it] = (sqrtf(red[0]) / denom < 1e-4f) ? 1.0f : 0.0f;
  }
}

__global__ void conv_scan(float* __restrict__ ws) {
  __shared__ unsigned char conv[MAXIT];
  const int tid = threadIdx.x;
  if (tid < MAXIT) conv[tid] = (ws[WS_CONVF + tid] != 0.0f) ? 1 : 0;
  __syncthreads();
  if (tid == 0) {
    int kstar = MAXIT;
    for (int it = 0; it < MAXIT; it++)
      if (conv[it]) { kstar = it; break; }
    *reinterpret_cast<int*>(&ws[WS_KSTAR]) = kstar;
  }
}

extern "C" void kernel_launch(void* const* d_in, const int* in_sizes, int n_in,
                              void* d_out, int out_size, void* d_ws, size_t ws_size,
                              hipStream_t stream) {
  const float* Drr = (const float*)d_in[0];
  const float* Dth = (const float*)d_in[1];
  const float* x   = (const float*)d_in[2];
  float* out = (float*)d_out;
  float* ws  = (float*)d_ws;

  setup1<<<1, 256, 0, stream>>>(Drr, Dth, ws);
  setup2<<<160, 256, 0, stream>>>(ws);
  setup3<<<100, 256, 0, stream>>>(ws);
  fista_kernel<<<GRID, NTHR, 0, stream>>>(x, out, ws, 0);
  conv_reduce<<<MAXIT, 512, 0, stream>>>(ws);
  conv_scan<<<1, 128, 0, stream>>>(ws);
  fista_kernel<<<GRID, NTHR, 0, stream>>>(x, out, ws, 1);
}

// Round 6
// 339.214 us; speedup vs baseline: 1.2214x; 1.1151x over previous
//
#include <hip/hip_runtime.h>
#include <hip/hip_bf16.h>

#define TT 36
#define KK 160
#define NPOLE 40
#define PP 4096
#define MAXIT 100
#define COLS 16
#define NW 10
#define NTHR 640
#define YS 168   // bf16 stride per column (padded from 160)
#define GRID 512

// ws float offsets
#define WS_LINV  0
#define WS_LAMBD 1
#define WS_TTS   2      // 100 floats
#define WS_KSTAR 128    // int
#define WS_FROB  132    // float, atomicAdd accumulator (setup only)
#define WS_CONVF 256    // 100 floats: convergence flags
#define WS_D     512    // 36*160 fp32
#define WS_A     6400   // 160*160 fp32 (DtD scratch)
#define WS_AH    32000  // 160*160 bf16 hi (as shorts)
#define WS_AL    44800  // 160*160 bf16 lo
#define WS_PART2 57600  // [it][bid] 100*512 floats
// end: 108800 floats = 435,200 B

typedef float  floatx4 __attribute__((ext_vector_type(4)));
typedef short  shortx8 __attribute__((ext_vector_type(8)));

__device__ __forceinline__ short f2bf(float v) {
  unsigned u = __float_as_uint(v);
  unsigned r = (u + 0x7FFFu + ((u >> 16) & 1u)) >> 16;  // RNE
  return (short)r;
}
__device__ __forceinline__ float bf2f(short s) {
  return __uint_as_float(((unsigned)(unsigned short)s) << 16);
}

// ---- setup 1: build normalized D, tts (1 block) ----
__global__ void setup1(const float* __restrict__ Drr,
                       const float* __restrict__ Dth,
                       float* __restrict__ ws) {
  __shared__ float Dl[TT * KK];
  __shared__ float Gl[KK];
  const int tid = threadIdx.x;
  if (tid == 0) ws[WS_FROB] = 0.f;

  for (int idx = tid; idx < TT * KK; idx += 256) {
    int i = idx / KK, k = idx % KK;
    int g = k / NPOLE, n = k % NPOLE;
    float rr = Drr[n], th = Dth[n];
    float pr = powf(rr, (float)i);
    float ang = (float)i * th;
    float tri = (g < 2) ? cosf(ang) : sinf(ang);
    float sgn = ((g & 1) && (i & 1)) ? -1.0f : 1.0f;
    Dl[idx] = pr * tri * sgn;
  }
  __syncthreads();
  if (tid < KK) {
    float s = 0.f;
    for (int i = 0; i < TT; i++) { float v = Dl[i * KK + tid]; s += v * v; }
    float gn = sqrtf(s);
    Gl[tid] = (gn == 0.f) ? sqrtf((float)TT) : gn;
  }
  __syncthreads();
  for (int idx = tid; idx < TT * KK; idx += 256)
    ws[WS_D + idx] = Dl[idx] / Gl[idx % KK];

  if (tid == 0) {
    double ts = 1.0;
    for (int k = 0; k < MAXIT; k++) {
      double tn = (1.0 + sqrt(1.0 + 4.0 * ts * ts)) * 0.5;
      ws[WS_TTS + k] = (float)((ts - 1.0) / tn);
      ts = tn;
    }
  }
}

// ---- setup 2: DtD row per block + Frobenius^2 accumulation (160 blocks) ----
__global__ void setup2(float* __restrict__ ws) {
  __shared__ float red[256];
  const int a = blockIdx.x, b = threadIdx.x;
  const float* D = &ws[WS_D];
  float ss = 0.f;
  if (b < KK) {
    float s = 0.f;
    for (int t = 0; t < TT; t++) s += D[t * KK + a] * D[t * KK + b];
    ws[WS_A + a * KK + b] = s;
    ss = s * s;
  }
  red[b] = ss;
  __syncthreads();
  for (int off = 128; off > 0; off >>= 1) {
    if (b < off) red[b] += red[b + off];
    __syncthreads();
  }
  if (b == 0) atomicAdd(&ws[WS_FROB], red[0]);
}

// ---- setup 3: A = I - DtD/L split to bf16 hi/lo (100 blocks) ----
__global__ void setup3(float* __restrict__ ws) {
  const int idx = blockIdx.x * 256 + threadIdx.x;
  const float linv = 1.0f / sqrtf(ws[WS_FROB]);
  short* AHs = (short*)&ws[WS_AH];
  short* ALs = (short*)&ws[WS_AL];
  if (idx < KK * KK) {
    int a = idx / KK, b = idx % KK;
    float av = ((a == b) ? 1.0f : 0.0f) - ws[WS_A + idx] * linv;
    short h = f2bf(av);
    AHs[idx] = h;
    ALs[idx] = f2bf(av - bf2f(h));
  }
  if (idx == 0) { ws[WS_LINV] = linv; ws[WS_LAMBD] = 0.1f * linv; }
}

// Block: 16 columns, 10 waves; wave w owns rows 16w..16w+15 (one fragment).
// A in registers (bf16 hi/lo); y double-buffered in LDS bf16 hi/lo.
// grid 512 -> 2 blocks/CU -> 20 waves/CU (5/SIMD) for latency hiding.
// No global memory ops inside the loop; per-iter norms via LDS, burst store.
__global__ __launch_bounds__(NTHR, 5)
void fista_kernel(const float* __restrict__ x, float* __restrict__ out,
                  float* __restrict__ ws, int mode) {
  __shared__ __align__(16) short ys[2][2][COLS * YS];  // 21,504 B
  __shared__ float red[2][NW];
  __shared__ float ttsl[MAXIT];
  __shared__ float parts[MAXIT];

  int niter = MAXIT;
  if (mode == 1) {
    int kstar = *(const int*)&ws[WS_KSTAR];
    if (kstar >= MAXIT - 1) return;
    niter = kstar + 1;
  }

  const int tid  = threadIdx.x;
  const int w    = tid >> 6;
  const int lane = tid & 63;
  const int quad = lane >> 4;
  const int l16  = lane & 15;
  const int bid  = blockIdx.x;
  const int c0   = bid * COLS;
  const int bb   = c0 / PP;
  const int p0   = c0 % PP;
  const float linv  = ws[WS_LINV];
  const float lambd = ws[WS_LAMBD];

  for (int i = tid; i < MAXIT; i += NTHR) ttsl[i] = ws[WS_TTS + i];

  // A fragments in registers: rows 16w..16w+15
  const short* AH = (const short*)&ws[WS_AH];
  const short* AL = (const short*)&ws[WS_AL];
  shortx8 ah[5], al[5];
#pragma unroll
  for (int kc = 0; kc < 5; kc++) {
    int off = (16 * w + l16) * KK + 32 * kc + 8 * quad;
    ah[kc] = *(const shortx8*)&AH[off];
    al[kc] = *(const shortx8*)&AL[off];
  }

  // dty (scaled by linv) in C layout: rows 16w+4quad+r, col l16
  const float* Dg = &ws[WS_D];
  float dty[4] = {0.f, 0.f, 0.f, 0.f};
  {
    const float* xcol = &x[(size_t)bb * TT * PP + p0 + l16];
    for (int t = 0; t < TT; t++) {
      float xv = xcol[(size_t)t * PP];
      float4 d0 = *(const float4*)&Dg[t * KK + 16 * w + 4 * quad];
      dty[0] = fmaf(d0.x, xv, dty[0]);
      dty[1] = fmaf(d0.y, xv, dty[1]);
      dty[2] = fmaf(d0.z, xv, dty[2]);
      dty[3] = fmaf(d0.w, xv, dty[3]);
    }
#pragma unroll
    for (int r = 0; r < 4; r++) dty[r] *= linv;
  }

  // zero buffer 0 (y=0); buffer 1 fully overwritten before first read
  {
    int* z = (int*)&ys[0][0][0];
    for (int i = tid; i < COLS * YS; i += NTHR) z[i] = 0;
  }
  float xo[4] = {0.f, 0.f, 0.f, 0.f};
  __syncthreads();

  int buf = 0;
  for (int it = 0; it < niter; it++) {
    const short* yh  = &ys[buf][0][0];
    const short* ylp = &ys[buf][1][0];
    const int cb = l16 * YS + 8 * quad;
    floatx4 accA = {0.f, 0.f, 0.f, 0.f};
    floatx4 accB = {0.f, 0.f, 0.f, 0.f};
    floatx4 accC = {0.f, 0.f, 0.f, 0.f};
#pragma unroll
    for (int kc = 0; kc < 5; kc++) {
      shortx8 bh = *(const shortx8*)&yh[cb + 32 * kc];
      shortx8 bl = *(const shortx8*)&ylp[cb + 32 * kc];
      accA = __builtin_amdgcn_mfma_f32_16x16x32_bf16(ah[kc], bh, accA, 0, 0, 0);
      accB = __builtin_amdgcn_mfma_f32_16x16x32_bf16(ah[kc], bl, accB, 0, 0, 0);
      accC = __builtin_amdgcn_mfma_f32_16x16x32_bf16(al[kc], bh, accC, 0, 0, 0);
    }

    const float tt = ttsl[it];
    const int nb = buf ^ 1;
    float lsum = 0.f;
    {
      float yn[4];
#pragma unroll
      for (int r = 0; r < 4; r++) {
        float v  = accA[r] + accB[r] + accC[r] + dty[r];
        float aa = fabsf(v) - lambd;
        float xv = (aa > 0.f) ? ((v < 0.f) ? -aa : aa) : 0.f;
        float dd = xv - xo[r];
        lsum = fmaf(dd, dd, lsum);
        yn[r] = fmaf(tt, dd, xv);
        xo[r] = xv;
      }
      __hip_bfloat162 h01 = __float22bfloat162_rn(make_float2(yn[0], yn[1]));
      __hip_bfloat162 h23 = __float22bfloat162_rn(make_float2(yn[2], yn[3]));
      unsigned u01 = *(unsigned*)&h01;
      unsigned u23 = *(unsigned*)&h23;
      float r0f = yn[0] - __uint_as_float(u01 << 16);
      float r1f = yn[1] - __uint_as_float(u01 & 0xffff0000u);
      float r2f = yn[2] - __uint_as_float(u23 << 16);
      float r3f = yn[3] - __uint_as_float(u23 & 0xffff0000u);
      __hip_bfloat162 l01 = __float22bfloat162_rn(make_float2(r0f, r1f));
      __hip_bfloat162 l23 = __float22bfloat162_rn(make_float2(r2f, r3f));
      const int ko = l16 * YS + 16 * w + 4 * quad;
      *(uint2*)&ys[nb][0][ko] = make_uint2(u01, u23);
      *(uint2*)&ys[nb][1][ko] = make_uint2(*(unsigned*)&l01, *(unsigned*)&l23);
    }

    if (mode == 0) {
#pragma unroll
      for (int off = 32; off > 0; off >>= 1) lsum += __shfl_down(lsum, off, 64);
      if (lane == 0) red[it & 1][w] = lsum;
    }
    __syncthreads();   // writes to buf^1 (+red) visible; reads of buf done
    if (mode == 0 && tid == 0) {
      float s = 0.f;
#pragma unroll
      for (int i = 0; i < NW; i++) s += red[it & 1][i];
      parts[it] = s;   // LDS only — no global traffic in the loop
    }
    buf = nb;
  }

#pragma unroll
  for (int r = 0; r < 4; r++)
    out[((size_t)bb * KK + 16 * w + 4 * quad + r) * PP + p0 + l16] = xo[r];

  if (mode == 0) {
    __syncthreads();   // parts[] complete
    if (tid < MAXIT) ws[WS_PART2 + tid * GRID + bid] = parts[tid];
  }
}

// ---- reduce per-iter norms across 512 blocks (100 blocks x 512 thr) ----
__global__ void conv_reduce(float* __restrict__ ws) {
  __shared__ float red[512];
  const int it = blockIdx.x, tid = threadIdx.x;
  red[tid] = ws[WS_PART2 + it * GRID + tid];
  __syncthreads();
  for (int off = 256; off > 0; off >>= 1) {
    if (tid < off) red[tid] += red[tid + off];
    __syncthreads();
  }
  if (tid == 0) {
    float denom = (it == 0) ? 4096.0f : 160.0f;
    ws[WS_CONVF + it] = (sqrtf(red[0]) / denom < 1e-4f) ? 1.0f : 0.0f;
  }
}

__global__ void conv_scan(float* __restrict__ ws) {
  __shared__ unsigned char conv[MAXIT];
  const int tid = threadIdx.x;
  if (tid < MAXIT) conv[tid] = (ws[WS_CONVF + tid] != 0.0f) ? 1 : 0;
  __syncthreads();
  if (tid == 0) {
    int kstar = MAXIT;
    for (int it = 0; it < MAXIT; it++)
      if (conv[it]) { kstar = it; break; }
    *reinterpret_cast<int*>(&ws[WS_KSTAR]) = kstar;
  }
}

extern "C" void kernel_launch(void* const* d_in, const int* in_sizes, int n_in,
                              void* d_out, int out_size, void* d_ws, size_t ws_size,
                              hipStream_t stream) {
  const float* Drr = (const float*)d_in[0];
  const float* Dth = (const float*)d_in[1];
  const float* x   = (const float*)d_in[2];
  float* out = (float*)d_out;
  float* ws  = (float*)d_ws;

  setup1<<<1, 256, 0, stream>>>(Drr, Dth, ws);
  setup2<<<160, 256, 0, stream>>>(ws);
  setup3<<<100, 256, 0, stream>>>(ws);
  fista_kernel<<<GRID, NTHR, 0, stream>>>(x, out, ws, 0);
  conv_reduce<<<MAXIT, 512, 0, stream>>>(ws);
  conv_scan<<<1, 128, 0, stream>>>(ws);
  fista_kernel<<<GRID, NTHR, 0, stream>>>(x, out, ws, 1);
}

// Round 7
// 258.607 us; speedup vs baseline: 1.6021x; 1.3117x over previous
//
#include <hip/hip_runtime.h>
#include <hip/hip_bf16.h>

#define TT 36
#define KK 160
#define NPOLE 40
#define PP 4096
#define MAXIT 100
#define COLS 16
#define NW 10
#define NTHR 640
#define YS 344   // shorts per col: [hi 0..159][pad 8][lo at +168 0..159][pad]
#define GRID 512

// ws float offsets
#define WS_LINV  0
#define WS_LAMBD 1
#define WS_TTS   2      // 100 floats
#define WS_KSTAR 128    // int
#define WS_FROB  132    // float, atomicAdd accumulator (setup only)
#define WS_CONVF 256    // 100 floats: convergence flags
#define WS_D     512    // 36*160 fp32
#define WS_A     6400   // 160*160 fp32 (DtD scratch)
#define WS_AH    32000  // 160*160 bf16 hi (as shorts)
#define WS_AL    44800  // 160*160 bf16 lo
#define WS_PART2 57600  // [it][bid] 100*512 floats

typedef float  floatx4 __attribute__((ext_vector_type(4)));
typedef short  shortx8 __attribute__((ext_vector_type(8)));

__device__ __forceinline__ short f2bf(float v) {
  unsigned u = __float_as_uint(v);
  unsigned r = (u + 0x7FFFu + ((u >> 16) & 1u)) >> 16;  // RNE
  return (short)r;
}
__device__ __forceinline__ float bf2f(short s) {
  return __uint_as_float(((unsigned)(unsigned short)s) << 16);
}

// wave64 sum via DPP (VALU pipe, no LDS): result uniform via readlane 63
__device__ __forceinline__ float wave_sum_dpp(float v) {
#define DPP_ADD(ctrl) \
  v += __int_as_float(__builtin_amdgcn_update_dpp(0, __float_as_int(v), ctrl, 0xf, 0xf, true))
  DPP_ADD(0x111);  // row_shr:1
  DPP_ADD(0x112);  // row_shr:2
  DPP_ADD(0x114);  // row_shr:4
  DPP_ADD(0x118);  // row_shr:8
  DPP_ADD(0x142);  // row_bcast:15
  DPP_ADD(0x143);  // row_bcast:31
#undef DPP_ADD
  return __int_as_float(__builtin_amdgcn_readlane(__float_as_int(v), 63));
}

// ---- setup 1: build normalized D, tts (1 block) ----
__global__ void setup1(const float* __restrict__ Drr,
                       const float* __restrict__ Dth,
                       float* __restrict__ ws) {
  __shared__ float Dl[TT * KK];
  __shared__ float Gl[KK];
  const int tid = threadIdx.x;
  if (tid == 0) ws[WS_FROB] = 0.f;

  for (int idx = tid; idx < TT * KK; idx += 256) {
    int i = idx / KK, k = idx % KK;
    int g = k / NPOLE, n = k % NPOLE;
    float rr = Drr[n], th = Dth[n];
    float pr = powf(rr, (float)i);
    float ang = (float)i * th;
    float tri = (g < 2) ? cosf(ang) : sinf(ang);
    float sgn = ((g & 1) && (i & 1)) ? -1.0f : 1.0f;
    Dl[idx] = pr * tri * sgn;
  }
  __syncthreads();
  if (tid < KK) {
    float s = 0.f;
    for (int i = 0; i < TT; i++) { float v = Dl[i * KK + tid]; s += v * v; }
    float gn = sqrtf(s);
    Gl[tid] = (gn == 0.f) ? sqrtf((float)TT) : gn;
  }
  __syncthreads();
  for (int idx = tid; idx < TT * KK; idx += 256)
    ws[WS_D + idx] = Dl[idx] / Gl[idx % KK];

  if (tid == 0) {
    double ts = 1.0;
    for (int k = 0; k < MAXIT; k++) {
      double tn = (1.0 + sqrt(1.0 + 4.0 * ts * ts)) * 0.5;
      ws[WS_TTS + k] = (float)((ts - 1.0) / tn);
      ts = tn;
    }
  }
}

// ---- setup 2: DtD row per block + Frobenius^2 accumulation (160 blocks) ----
__global__ void setup2(float* __restrict__ ws) {
  __shared__ float red[256];
  const int a = blockIdx.x, b = threadIdx.x;
  const float* D = &ws[WS_D];
  float ss = 0.f;
  if (b < KK) {
    float s = 0.f;
    for (int t = 0; t < TT; t++) s += D[t * KK + a] * D[t * KK + b];
    ws[WS_A + a * KK + b] = s;
    ss = s * s;
  }
  red[b] = ss;
  __syncthreads();
  for (int off = 128; off > 0; off >>= 1) {
    if (b < off) red[b] += red[b + off];
    __syncthreads();
  }
  if (b == 0) atomicAdd(&ws[WS_FROB], red[0]);
}

// ---- setup 3: A = I - DtD/L split to bf16 hi/lo (100 blocks) ----
__global__ void setup3(float* __restrict__ ws) {
  const int idx = blockIdx.x * 256 + threadIdx.x;
  const float linv = 1.0f / sqrtf(ws[WS_FROB]);
  short* AHs = (short*)&ws[WS_AH];
  short* ALs = (short*)&ws[WS_AL];
  if (idx < KK * KK) {
    int a = idx / KK, b = idx % KK;
    float av = ((a == b) ? 1.0f : 0.0f) - ws[WS_A + idx] * linv;
    short h = f2bf(av);
    AHs[idx] = h;
    ALs[idx] = f2bf(av - bf2f(h));
  }
  if (idx == 0) { ws[WS_LINV] = linv; ws[WS_LAMBD] = 0.1f * linv; }
}

// Block: 16 columns, 10 waves; wave w owns rows 16w..16w+15.
// A in registers (bf16 hi/lo); y double-buffered in LDS (hi/lo interleaved
// per column). Per-32k-chunk zero flags let waves skip DS reads + MFMAs for
// all-zero y chunks (bit-identical: skipped contribution is exactly 0).
__global__ __launch_bounds__(NTHR, 5)
void fista_kernel(const float* __restrict__ x, float* __restrict__ out,
                  float* __restrict__ ws, int mode) {
  __shared__ __align__(16) short ys[2][COLS * YS];  // 22,016 B
  __shared__ __align__(16) unsigned char flagbuf[2][16];
  __shared__ float red[2][NW];
  __shared__ float ttsl[MAXIT];
  __shared__ float parts[MAXIT];

  int niter = MAXIT;
  if (mode == 1) {
    int kstar = *(const int*)&ws[WS_KSTAR];
    if (kstar >= MAXIT - 1) return;
    niter = kstar + 1;
  }

  const int tid  = threadIdx.x;
  const int w    = tid >> 6;
  const int lane = tid & 63;
  const int quad = lane >> 4;
  const int l16  = lane & 15;
  const int bid  = blockIdx.x;
  const int c0   = bid * COLS;
  const int bb   = c0 / PP;
  const int p0   = c0 % PP;
  const float linv  = ws[WS_LINV];
  const float lambd = ws[WS_LAMBD];

  for (int i = tid; i < MAXIT; i += NTHR) ttsl[i] = ws[WS_TTS + i];

  // A fragments in registers: rows 16w..16w+15
  const short* AH = (const short*)&ws[WS_AH];
  const short* AL = (const short*)&ws[WS_AL];
  shortx8 ah[5], al[5];
#pragma unroll
  for (int kc = 0; kc < 5; kc++) {
    int off = (16 * w + l16) * KK + 32 * kc + 8 * quad;
    ah[kc] = *(const shortx8*)&AH[off];
    al[kc] = *(const shortx8*)&AL[off];
  }

  // dty (scaled by linv) in C layout: rows 16w+4quad+r, col l16
  const float* Dg = &ws[WS_D];
  float dty[4] = {0.f, 0.f, 0.f, 0.f};
  {
    const float* xcol = &x[(size_t)bb * TT * PP + p0 + l16];
    for (int t = 0; t < TT; t++) {
      float xv = xcol[(size_t)t * PP];
      float4 d0 = *(const float4*)&Dg[t * KK + 16 * w + 4 * quad];
      dty[0] = fmaf(d0.x, xv, dty[0]);
      dty[1] = fmaf(d0.y, xv, dty[1]);
      dty[2] = fmaf(d0.z, xv, dty[2]);
      dty[3] = fmaf(d0.w, xv, dty[3]);
    }
#pragma unroll
    for (int r = 0; r < 4; r++) dty[r] *= linv;
  }

  // zero buffer 0 (y=0) and its flags (all chunks inactive -> full skip)
  {
    int* z = (int*)&ys[0][0];
    for (int i = tid; i < COLS * YS / 2; i += NTHR) z[i] = 0;
    if (tid < 16) flagbuf[0][tid] = 0;
  }
  float xo[4] = {0.f, 0.f, 0.f, 0.f};
  __syncthreads();

  int buf = 0;
  for (int it = 0; it < niter; it++) {
    // chunk-activity flags (wave-uniform): kc active iff bytes 2kc|2kc+1
    uint4 fl = *(const uint4*)&flagbuf[buf][0];
    const short* yb = &ys[buf][0];
    const int cb = l16 * YS + 8 * quad;

    floatx4 accM = {dty[0], dty[1], dty[2], dty[3]};
    floatx4 accC = {0.f, 0.f, 0.f, 0.f};
#define KC_STEP(kc, actv)                                                    \
    if (actv) {                                                              \
      shortx8 bh = *(const shortx8*)&yb[cb + 32 * kc];                       \
      shortx8 bl = *(const shortx8*)&yb[cb + 32 * kc + 168];                 \
      accM = __builtin_amdgcn_mfma_f32_16x16x32_bf16(ah[kc], bh, accM, 0, 0, 0); \
      accC = __builtin_amdgcn_mfma_f32_16x16x32_bf16(ah[kc], bl, accC, 0, 0, 0); \
      accC = __builtin_amdgcn_mfma_f32_16x16x32_bf16(al[kc], bh, accC, 0, 0, 0); \
    }
    KC_STEP(0, (fl.x & 0xFFFFu))
    KC_STEP(1, (fl.x >> 16))
    KC_STEP(2, (fl.y & 0xFFFFu))
    KC_STEP(3, (fl.y >> 16))
    KC_STEP(4, (fl.z & 0xFFFFu))
#undef KC_STEP

    const float tt = ttsl[it];
    const int nb = buf ^ 1;
    float lsum = 0.f;
    unsigned nzbits;
    {
      float yn[4];
#pragma unroll
      for (int r = 0; r < 4; r++) {
        float v  = accM[r] + accC[r];
        float aa = fabsf(v) - lambd;
        float xv = (aa > 0.f) ? ((v < 0.f) ? -aa : aa) : 0.f;
        float dd = xv - xo[r];
        lsum = fmaf(dd, dd, lsum);
        yn[r] = fmaf(tt, dd, xv);
        xo[r] = xv;
      }
      __hip_bfloat162 h01 = __float22bfloat162_rn(make_float2(yn[0], yn[1]));
      __hip_bfloat162 h23 = __float22bfloat162_rn(make_float2(yn[2], yn[3]));
      unsigned u01 = *(unsigned*)&h01;
      unsigned u23 = *(unsigned*)&h23;
      float r0f = yn[0] - __uint_as_float(u01 << 16);
      float r1f = yn[1] - __uint_as_float(u01 & 0xffff0000u);
      float r2f = yn[2] - __uint_as_float(u23 << 16);
      float r3f = yn[3] - __uint_as_float(u23 & 0xffff0000u);
      __hip_bfloat162 l01 = __float22bfloat162_rn(make_float2(r0f, r1f));
      __hip_bfloat162 l23 = __float22bfloat162_rn(make_float2(r2f, r3f));
      unsigned v01 = *(unsigned*)&l01;
      unsigned v23 = *(unsigned*)&l23;
      nzbits = u01 | u23 | v01 | v23;
      const int ko = l16 * YS + 16 * w + 4 * quad;   // hi plane
      *(uint2*)&ys[nb][ko]       = make_uint2(u01, u23);
      *(uint2*)&ys[nb][ko + 168] = make_uint2(v01, v23);   // lo plane (+336 B)
    }

    // per-wave chunk flag (wave covers k in [16w,16w+16) -> chunk w>>1)
    unsigned long long ball = __ballot(nzbits != 0);
    if (lane == 0) flagbuf[nb][w] = (unsigned char)(ball != 0ULL);

    if (mode == 0) {
      float wsum = wave_sum_dpp(lsum);   // VALU-only reduction
      if (lane == 0) red[it & 1][w] = wsum;
    }
    __syncthreads();   // y/flags writes to buf^1 (+red) visible; reads done
    if (mode == 0 && tid == 0) {
      float s = 0.f;
#pragma unroll
      for (int i = 0; i < NW; i++) s += red[it & 1][i];
      parts[it] = s;
    }
    buf = nb;
  }

#pragma unroll
  for (int r = 0; r < 4; r++)
    out[((size_t)bb * KK + 16 * w + 4 * quad + r) * PP + p0 + l16] = xo[r];

  if (mode == 0) {
    __syncthreads();   // parts[] complete
    if (tid < MAXIT) ws[WS_PART2 + tid * GRID + bid] = parts[tid];
  }
}

// ---- reduce per-iter norms across 512 blocks (100 blocks x 512 thr) ----
__global__ void conv_reduce(float* __restrict__ ws) {
  __shared__ float red[512];
  const int it = blockIdx.x, tid = threadIdx.x;
  red[tid] = ws[WS_PART2 + it * GRID + tid];
  __syncthreads();
  for (int off = 256; off > 0; off >>= 1) {
    if (tid < off) red[tid] += red[tid + off];
    __syncthreads();
  }
  if (tid == 0) {
    float denom = (it == 0) ? 4096.0f : 160.0f;
    ws[WS_CONVF + it] = (sqrtf(red[0]) / denom < 1e-4f) ? 1.0f : 0.0f;
  }
}

__global__ void conv_scan(float* __restrict__ ws) {
  __shared__ unsigned char conv[MAXIT];
  const int tid = threadIdx.x;
  if (tid < MAXIT) conv[tid] = (ws[WS_CONVF + tid] != 0.0f) ? 1 : 0;
  __syncthreads();
  if (tid == 0) {
    int kstar = MAXIT;
    for (int it = 0; it < MAXIT; it++)
      if (conv[it]) { kstar = it; break; }
    *reinterpret_cast<int*>(&ws[WS_KSTAR]) = kstar;
  }
}

extern "C" void kernel_launch(void* const* d_in, const int* in_sizes, int n_in,
                              void* d_out, int out_size, void* d_ws, size_t ws_size,
                              hipStream_t stream) {
  const float* Drr = (const float*)d_in[0];
  const float* Dth = (const float*)d_in[1];
  const float* x   = (const float*)d_in[2];
  float* out = (float*)d_out;
  float* ws  = (float*)d_ws;

  setup1<<<1, 256, 0, stream>>>(Drr, Dth, ws);
  setup2<<<160, 256, 0, stream>>>(ws);
  setup3<<<100, 256, 0, stream>>>(ws);
  fista_kernel<<<GRID, NTHR, 0, stream>>>(x, out, ws, 0);
  conv_reduce<<<MAXIT, 512, 0, stream>>>(ws);
  conv_scan<<<1, 128, 0, stream>>>(ws);
  fista_kernel<<<GRID, NTHR, 0, stream>>>(x, out, ws, 1);
}

// Round 8
// 246.345 us; speedup vs baseline: 1.6819x; 1.0498x over previous
//
#include <hip/hip_runtime.h>
#include <hip/hip_bf16.h>

#define TT 36
#define KK 160
#define NPOLE 40
#define PP 4096
#define MAXIT 100
#define COLS 16    // columns per group
#define NG 2       // independent groups per block
#define NWPG 5     // waves per group (rows 32/wave)
#define NW 10
#define NTHR 640
#define YS 344     // shorts per col: [hi 0..159][pad][lo at +168][pad]
#define GRID 256

// ws float offsets
#define WS_LINV  0
#define WS_LAMBD 1
#define WS_TTS   2
#define WS_KSTAR 128
#define WS_FROB  132
#define WS_CONVF 256
#define WS_D     512
#define WS_A     6400
#define WS_AH    32000
#define WS_AL    44800
#define WS_PART2 57600  // [it][bid] 100*256 floats

typedef float  floatx4 __attribute__((ext_vector_type(4)));
typedef short  shortx8 __attribute__((ext_vector_type(8)));

__device__ __forceinline__ short f2bf(float v) {
  unsigned u = __float_as_uint(v);
  unsigned r = (u + 0x7FFFu + ((u >> 16) & 1u)) >> 16;  // RNE
  return (short)r;
}
__device__ __forceinline__ float bf2f(short s) {
  return __uint_as_float(((unsigned)(unsigned short)s) << 16);
}

__device__ __forceinline__ float wave_sum_dpp(float v) {
#define DPP_ADD(ctrl) \
  v += __int_as_float(__builtin_amdgcn_update_dpp(0, __float_as_int(v), ctrl, 0xf, 0xf, true))
  DPP_ADD(0x111);
  DPP_ADD(0x112);
  DPP_ADD(0x114);
  DPP_ADD(0x118);
  DPP_ADD(0x142);
  DPP_ADD(0x143);
#undef DPP_ADD
  return __int_as_float(__builtin_amdgcn_readlane(__float_as_int(v), 63));
}

__global__ void setup1(const float* __restrict__ Drr,
                       const float* __restrict__ Dth,
                       float* __restrict__ ws) {
  __shared__ float Dl[TT * KK];
  __shared__ float Gl[KK];
  const int tid = threadIdx.x;
  if (tid == 0) ws[WS_FROB] = 0.f;

  for (int idx = tid; idx < TT * KK; idx += 256) {
    int i = idx / KK, k = idx % KK;
    int g = k / NPOLE, n = k % NPOLE;
    float rr = Drr[n], th = Dth[n];
    float pr = powf(rr, (float)i);
    float ang = (float)i * th;
    float tri = (g < 2) ? cosf(ang) : sinf(ang);
    float sgn = ((g & 1) && (i & 1)) ? -1.0f : 1.0f;
    Dl[idx] = pr * tri * sgn;
  }
  __syncthreads();
  if (tid < KK) {
    float s = 0.f;
    for (int i = 0; i < TT; i++) { float v = Dl[i * KK + tid]; s += v * v; }
    float gn = sqrtf(s);
    Gl[tid] = (gn == 0.f) ? sqrtf((float)TT) : gn;
  }
  __syncthreads();
  for (int idx = tid; idx < TT * KK; idx += 256)
    ws[WS_D + idx] = Dl[idx] / Gl[idx % KK];

  if (tid == 0) {
    double ts = 1.0;
    for (int k = 0; k < MAXIT; k++) {
      double tn = (1.0 + sqrt(1.0 + 4.0 * ts * ts)) * 0.5;
      ws[WS_TTS + k] = (float)((ts - 1.0) / tn);
      ts = tn;
    }
  }
}

__global__ void setup2(float* __restrict__ ws) {
  __shared__ float red[256];
  const int a = blockIdx.x, b = threadIdx.x;
  const float* D = &ws[WS_D];
  float ss = 0.f;
  if (b < KK) {
    float s = 0.f;
    for (int t = 0; t < TT; t++) s += D[t * KK + a] * D[t * KK + b];
    ws[WS_A + a * KK + b] = s;
    ss = s * s;
  }
  red[b] = ss;
  __syncthreads();
  for (int off = 128; off > 0; off >>= 1) {
    if (b < off) red[b] += red[b + off];
    __syncthreads();
  }
  if (b == 0) atomicAdd(&ws[WS_FROB], red[0]);
}

__global__ void setup3(float* __restrict__ ws) {
  const int idx = blockIdx.x * 256 + threadIdx.x;
  const float linv = 1.0f / sqrtf(ws[WS_FROB]);
  short* AHs = (short*)&ws[WS_AH];
  short* ALs = (short*)&ws[WS_AL];
  if (idx < KK * KK) {
    int a = idx / KK, b = idx % KK;
    float av = ((a == b) ? 1.0f : 0.0f) - ws[WS_A + idx] * linv;
    short h = f2bf(av);
    AHs[idx] = h;
    ALs[idx] = f2bf(av - bf2f(h));
  }
  if (idx == 0) { ws[WS_LINV] = linv; ws[WS_LAMBD] = 0.1f * linv; }
}

// Block: 32 cols = 2 independent 16-col groups of 5 waves (32 rows/wave).
// A (bf16 hi/lo) in registers; y double-buffered LDS per group. NO
// __syncthreads in the loop: per-group LDS counter (release add after
// y-writes, acquire spin before reads). Per-wave norm partials to private
// wred slots; reduced once at the end.
__global__ __launch_bounds__(NTHR, 2)
void fista_kernel(const float* __restrict__ x, float* __restrict__ out,
                  float* __restrict__ ws, int mode) {
  __shared__ __align__(16) short ys[NG][2][COLS * YS];  // 44,032 B
  __shared__ float wred[NW][MAXIT];                     // 4,000 B
  __shared__ float ttsl[MAXIT];
  __shared__ unsigned cnt[NG];

  int niter = MAXIT;
  if (mode == 1) {
    int kstar = *(const int*)&ws[WS_KSTAR];
    if (kstar >= MAXIT - 1) return;
    niter = kstar + 1;
  }

  const int tid  = threadIdx.x;
  const int w    = tid >> 6;
  const int lane = tid & 63;
  const int quad = lane >> 4;
  const int l16  = lane & 15;
  const int g    = w / NWPG;       // group 0/1
  const int v    = w % NWPG;       // rowgroup within group: rows 32v..32v+31
  const int bid  = blockIdx.x;
  const int bb   = (bid * 32) / PP;
  const int p0   = (bid * 32) % PP + 16 * g;
  const float linv  = ws[WS_LINV];
  const float lambd = ws[WS_LAMBD];

  for (int i = tid; i < MAXIT; i += NTHR) ttsl[i] = ws[WS_TTS + i];

  // A fragments in registers: rowset rs covers rows 32v+16rs..+15
  const short* AH = (const short*)&ws[WS_AH];
  const short* AL = (const short*)&ws[WS_AL];
  shortx8 ah[2][5], al[2][5];
#pragma unroll
  for (int rs = 0; rs < 2; rs++)
#pragma unroll
    for (int kc = 0; kc < 5; kc++) {
      int off = (32 * v + 16 * rs + l16) * KK + 32 * kc + 8 * quad;
      ah[rs][kc] = *(const shortx8*)&AH[off];
      al[rs][kc] = *(const shortx8*)&AL[off];
    }

  // dty (scaled by linv): rows 32v+16rs+4quad+r, col l16 of this group
  const float* Dg = &ws[WS_D];
  float dty[2][4] = {{0.f,0.f,0.f,0.f},{0.f,0.f,0.f,0.f}};
  {
    const float* xcol = &x[(size_t)bb * TT * PP + p0 + l16];
    for (int t = 0; t < TT; t++) {
      float xv = xcol[(size_t)t * PP];
      float4 d0 = *(const float4*)&Dg[t * KK + 32 * v + 4 * quad];
      float4 d1 = *(const float4*)&Dg[t * KK + 32 * v + 16 + 4 * quad];
      dty[0][0] = fmaf(d0.x, xv, dty[0][0]);
      dty[0][1] = fmaf(d0.y, xv, dty[0][1]);
      dty[0][2] = fmaf(d0.z, xv, dty[0][2]);
      dty[0][3] = fmaf(d0.w, xv, dty[0][3]);
      dty[1][0] = fmaf(d1.x, xv, dty[1][0]);
      dty[1][1] = fmaf(d1.y, xv, dty[1][1]);
      dty[1][2] = fmaf(d1.z, xv, dty[1][2]);
      dty[1][3] = fmaf(d1.w, xv, dty[1][3]);
    }
#pragma unroll
    for (int rs = 0; rs < 2; rs++)
#pragma unroll
      for (int r = 0; r < 4; r++) dty[rs][r] *= linv;
  }

  // zero buffer 0 of both groups; counters; one barrier total
  {
    int* z = (int*)&ys[0][0][0];
    for (int i = tid; i < NG * 2 * COLS * YS / 2; i += NTHR) z[i] = 0;
    if (tid < NG) cnt[tid] = 0;
  }
  float xo[2][4] = {{0.f,0.f,0.f,0.f},{0.f,0.f,0.f,0.f}};
  __syncthreads();

  for (int it = 0; it < niter; it++) {
    if (it > 0) {
      const unsigned tgt = (unsigned)(NWPG * it);
      while (__atomic_load_n(&cnt[g], __ATOMIC_ACQUIRE) < tgt) { }
    }
    const short* yb = &ys[g][it & 1][0];
    const int cb = l16 * YS + 8 * quad;
    floatx4 accM[2] = {{dty[0][0], dty[0][1], dty[0][2], dty[0][3]},
                       {dty[1][0], dty[1][1], dty[1][2], dty[1][3]}};
    floatx4 accB[2] = {{0.f,0.f,0.f,0.f},{0.f,0.f,0.f,0.f}};
    floatx4 accC[2] = {{0.f,0.f,0.f,0.f},{0.f,0.f,0.f,0.f}};
#pragma unroll
    for (int kc = 0; kc < 5; kc++) {
      shortx8 bh = *(const shortx8*)&yb[cb + 32 * kc];
      shortx8 bl = *(const shortx8*)&yb[cb + 32 * kc + 168];
#pragma unroll
      for (int rs = 0; rs < 2; rs++) {
        accM[rs] = __builtin_amdgcn_mfma_f32_16x16x32_bf16(ah[rs][kc], bh, accM[rs], 0, 0, 0);
        accB[rs] = __builtin_amdgcn_mfma_f32_16x16x32_bf16(ah[rs][kc], bl, accB[rs], 0, 0, 0);
        accC[rs] = __builtin_amdgcn_mfma_f32_16x16x32_bf16(al[rs][kc], bh, accC[rs], 0, 0, 0);
      }
    }

    const float tt = ttsl[it];
    short* yw = &ys[g][(it & 1) ^ 1][0];
    float lsum = 0.f;
#pragma unroll
    for (int rs = 0; rs < 2; rs++) {
      float yn[4];
#pragma unroll
      for (int r = 0; r < 4; r++) {
        float vv = accM[rs][r] + accB[rs][r] + accC[rs][r];
        float aa = fabsf(vv) - lambd;
        float xv = (aa > 0.f) ? ((vv < 0.f) ? -aa : aa) : 0.f;
        float dd = xv - xo[rs][r];
        lsum = fmaf(dd, dd, lsum);
        yn[r] = fmaf(tt, dd, xv);
        xo[rs][r] = xv;
      }
      __hip_bfloat162 h01 = __float22bfloat162_rn(make_float2(yn[0], yn[1]));
      __hip_bfloat162 h23 = __float22bfloat162_rn(make_float2(yn[2], yn[3]));
      unsigned u01 = *(unsigned*)&h01;
      unsigned u23 = *(unsigned*)&h23;
      float r0f = yn[0] - __uint_as_float(u01 << 16);
      float r1f = yn[1] - __uint_as_float(u01 & 0xffff0000u);
      float r2f = yn[2] - __uint_as_float(u23 << 16);
      float r3f = yn[3] - __uint_as_float(u23 & 0xffff0000u);
      __hip_bfloat162 l01 = __float22bfloat162_rn(make_float2(r0f, r1f));
      __hip_bfloat162 l23 = __float22bfloat162_rn(make_float2(r2f, r3f));
      const int ko = l16 * YS + 32 * v + 16 * rs + 4 * quad;
      *(uint2*)&yw[ko]       = make_uint2(u01, u23);
      *(uint2*)&yw[ko + 168] = make_uint2(*(unsigned*)&l01, *(unsigned*)&l23);
    }

    if (mode == 0) {
      float wsum = wave_sum_dpp(lsum);
      if (lane == 0) wred[w][it] = wsum;   // private slot, no sync needed
    }
    // release: y-writes (and wred) drain before the count bumps
    if (lane == 0) __atomic_fetch_add(&cnt[g], 1u, __ATOMIC_RELEASE);
  }

#pragma unroll
  for (int rs = 0; rs < 2; rs++)
#pragma unroll
    for (int r = 0; r < 4; r++)
      out[((size_t)bb * KK + 32 * v + 16 * rs + 4 * quad + r) * PP + p0 + l16] = xo[rs][r];

  if (mode == 0) {
    __syncthreads();   // all wred slots complete
    for (int it = tid; it < MAXIT; it += NTHR) {
      float s = 0.f;
#pragma unroll
      for (int i = 0; i < NW; i++) s += wred[i][it];
      ws[WS_PART2 + it * GRID + bid] = s;
    }
  }
}

__global__ void conv_reduce(float* __restrict__ ws) {
  __shared__ float red[GRID];
  const int it = blockIdx.x, tid = threadIdx.x;
  red[tid] = ws[WS_PART2 + it * GRID + tid];
  __syncthreads();
  for (int off = GRID / 2; off > 0; off >>= 1) {
    if (tid < off) red[tid] += red[tid + off];
    __syncthreads();
  }
  if (tid == 0) {
    float denom = (it == 0) ? 4096.0f : 160.0f;
    ws[WS_CONVF + it] = (sqrtf(red[0]) / denom < 1e-4f) ? 1.0f : 0.0f;
  }
}

__global__ void conv_scan(float* __restrict__ ws) {
  __shared__ unsigned char conv[MAXIT];
  const int tid = threadIdx.x;
  if (tid < MAXIT) conv[tid] = (ws[WS_CONVF + tid] != 0.0f) ? 1 : 0;
  __syncthreads();
  if (tid == 0) {
    int kstar = MAXIT;
    for (int it = 0; it < MAXIT; it++)
      if (conv[it]) { kstar = it; break; }
    *reinterpret_cast<int*>(&ws[WS_KSTAR]) = kstar;
  }
}

extern "C" void kernel_launch(void* const* d_in, const int* in_sizes, int n_in,
                              void* d_out, int out_size, void* d_ws, size_t ws_size,
                              hipStream_t stream) {
  const float* Drr = (const float*)d_in[0];
  const float* Dth = (const float*)d_in[1];
  const float* x   = (const float*)d_in[2];
  float* out = (float*)d_out;
  float* ws  = (float*)d_ws;

  setup1<<<1, 256, 0, stream>>>(Drr, Dth, ws);
  setup2<<<160, 256, 0, stream>>>(ws);
  setup3<<<100, 256, 0, stream>>>(ws);
  fista_kernel<<<GRID, NTHR, 0, stream>>>(x, out, ws, 0);
  conv_reduce<<<MAXIT, GRID, 0, stream>>>(ws);
  conv_scan<<<1, 128, 0, stream>>>(ws);
  fista_kernel<<<GRID, NTHR, 0, stream>>>(x, out, ws, 1);
}